// Round 9
// baseline (178.498 us; speedup 1.0000x reference)
//
#include <hip/hip_runtime.h>

// B = IN = OUT = 512; T from out_size.
// v_t = P_t @ x^T [OUT,B]; G = x@x^T [B,B]
//   u = k*(M*e^{-t} + a*v);  h = (u>0);  s = (u>0.2)
//   v' = d*v + e*(h@G + bt*colsum(G))
// Round-9: snn keeps the thread-per-column + ballot-mask skeleton, but the
// delta-apply phase builds a compact LDS list of flipped rows (ballot-prefix)
// and applies it with COUNTED loops -> compiler-unrolled, pipelined G loads
// (round-8's ctz while-loops serialized ~200cy L2 loads). Summation order is
// identical to round 8 (ascending rows per word, sign = new h bit).
// GEMM: 32x64 tiles, grid 384, 2x4 micro, register double-buffered staging.

#define NN 512

// ---- Stacked NT GEMM: grid 384 = 3 outputs x (16 row-tiles x 8 col-tiles).
// out 0: M = relu(W·x^T + b); out 1: V0 = P0·x^T; out 2: G = x·x^T.
// 32x64 tile, 256 thr, 2x4 micro, KC=32, reg double-buffer.
__global__ __launch_bounds__(256) void gemm_stack2_kernel(
    const float* __restrict__ x, const float* __restrict__ W,
    const float* __restrict__ P0, const float* __restrict__ bias,
    float* __restrict__ M, float* __restrict__ V0, float* __restrict__ G)
{
    const int tid = threadIdx.x;
    const int bid = blockIdx.x;          // 0..383
    const int out = bid >> 7;            // 0..2
    const int tl = bid & 127;            // 0..127
    const int rb = (tl >> 3) << 5;       // 16 row-tiles of 32
    const int cb = (tl & 7) << 6;        // 8 col-tiles of 64

    const float* A = ((out == 0) ? W : (out == 1) ? P0 : x) + (size_t)rb * NN;
    float* D = (out == 0) ? M : (out == 1) ? V0 : G;

    const int tx = tid & 15;             // cols 4tx..4tx+3
    const int ty = tid >> 4;             // rows 2ty, 2ty+1

    __shared__ float At[32][36];         // [k][row], stride 36 keeps 8B align
    __shared__ float Bt[32][68];         // [k][col], stride 68 keeps 16B align

    const int ar = tid >> 3;             // 0..31
    const int ak = (tid & 7) << 2;       // 0,4,...,28
    const int br = tid >> 2;             // 0..63
    const int bk = (tid & 3) << 3;       // 0,8,16,24

    float acc[2][4] = {{0.f, 0.f, 0.f, 0.f}, {0.f, 0.f, 0.f, 0.f}};

    // prologue: load chunk 0 into registers
    float4 av4 = *(const float4*)(A + (size_t)ar * NN + ak);
    float4 bv4a = *(const float4*)(x + (size_t)(cb + br) * NN + bk);
    float4 bv4b = *(const float4*)(x + (size_t)(cb + br) * NN + bk + 4);

    for (int c = 0; c < 16; ++c) {
        __syncthreads();
        At[ak + 0][ar] = av4.x; At[ak + 1][ar] = av4.y;
        At[ak + 2][ar] = av4.z; At[ak + 3][ar] = av4.w;
        Bt[bk + 0][br] = bv4a.x; Bt[bk + 1][br] = bv4a.y;
        Bt[bk + 2][br] = bv4a.z; Bt[bk + 3][br] = bv4a.w;
        Bt[bk + 4][br] = bv4b.x; Bt[bk + 5][br] = bv4b.y;
        Bt[bk + 6][br] = bv4b.z; Bt[bk + 7][br] = bv4b.w;
        __syncthreads();

        if (c < 15) {   // issue next-chunk loads; latency hides under compute
            const int k0 = (c + 1) << 5;
            av4 = *(const float4*)(A + (size_t)ar * NN + k0 + ak);
            bv4a = *(const float4*)(x + (size_t)(cb + br) * NN + k0 + bk);
            bv4b = *(const float4*)(x + (size_t)(cb + br) * NN + k0 + bk + 4);
        }

#pragma unroll
        for (int k = 0; k < 32; ++k) {
            const float2 av = *(const float2*)&At[k][2 * ty];
            const float4 bv = *(const float4*)&Bt[k][4 * tx];
            acc[0][0] = fmaf(av.x, bv.x, acc[0][0]);
            acc[0][1] = fmaf(av.x, bv.y, acc[0][1]);
            acc[0][2] = fmaf(av.x, bv.z, acc[0][2]);
            acc[0][3] = fmaf(av.x, bv.w, acc[0][3]);
            acc[1][0] = fmaf(av.y, bv.x, acc[1][0]);
            acc[1][1] = fmaf(av.y, bv.y, acc[1][1]);
            acc[1][2] = fmaf(av.y, bv.z, acc[1][2]);
            acc[1][3] = fmaf(av.y, bv.w, acc[1][3]);
        }
    }

#pragma unroll
    for (int i = 0; i < 2; ++i) {
        const int r = rb + 2 * ty + i;
        float4 o = make_float4(acc[i][0], acc[i][1], acc[i][2], acc[i][3]);
        if (out == 0) {
            const float bb = bias[r];
            o.x = fmaxf(o.x + bb, 0.f); o.y = fmaxf(o.y + bb, 0.f);
            o.z = fmaxf(o.z + bb, 0.f); o.w = fmaxf(o.w + bb, 0.f);
        }
        *(float4*)(D + (size_t)r * NN + cb + 4 * tx) = o;
    }
}

// ---- colsum: 8 blocks x 256 thr
__global__ __launch_bounds__(256) void colsum_kernel(
    const float* __restrict__ G, float* __restrict__ gs)
{
    __shared__ float red[4][64];
    const int tid = threadIdx.x;
    const int c = (blockIdx.x << 6) + (tid & 63);
    const int g = tid >> 6;
    float s = 0.f;
    for (int bp = 128 * g; bp < 128 * g + 128; ++bp) s += G[(size_t)bp * NN + c];
    if (g > 0) red[g][tid & 63] = s;
    __syncthreads();
    if (g == 0) gs[c] = ((s + red[1][tid & 63]) + red[2][tid & 63]) + red[3][tid & 63];
}

// ---- Main recurrence: 512 blocks x 512 threads. Thread owns col c = tid.
// Wave w publishes 64 h-bits via ballot; frozen steps: 1 barrier + flag check.
// Change steps: each wave converts its xor word into a compact LDS list
// segment (ballot prefix), then ALL threads apply the list with counted,
// unrollable loops of independent coalesced G loads.
__global__ __launch_bounds__(512) void snn_bits3_kernel(
    const float* __restrict__ M, const float* __restrict__ G,
    const float* __restrict__ V0, const float* __restrict__ gs,
    const float* __restrict__ alpha, const float* __restrict__ eta,
    const float* __restrict__ beta, unsigned* __restrict__ sp, int T)
{
    const int tid = threadIdx.x;
    const int w = tid >> 6;
    const int lane = tid & 63;
    const int r = blockIdx.x;

    __shared__ unsigned long long lmask[2][8];
    __shared__ unsigned long long lflag[2];
    __shared__ unsigned long long omask[8];      // last-applied h words
    __shared__ unsigned short list[512];         // row(9b) | sign(bit15)
    __shared__ int wcnt[8];

    const float a = alpha[0], e = eta[0], bt = beta[0];
    const float kk = 0.2f;
    const float dd = 0.36787944117144233f;   // exp(-1)
    const float Vth = 0.2f;

    const size_t rc = (size_t)r * NN + tid;
    const float m = M[rc];
    float v = V0[rc];
    const float cg = e * bt * gs[tid];
    const float* Gc = G + tid;

    if (tid < 8) omask[tid] = 0ull;          // acc==0 <-> h==0 baseline: exact
    __syncthreads();

    float acc = 0.f;
    float em = 1.0f;

    for (int t = 0; t < T; ++t) {
        const float u = kk * fmaf(a, v, m * em);
        const unsigned long long hb = __ballot(u > 0.f);
        const unsigned long long sb = __ballot(u > Vth);
        const int p = t & 1;
        if (lane == 0) {
            lmask[p][w] = hb;
            ((unsigned char*)&lflag[p])[w] = (hb != omask[w]) ? (unsigned char)1 : (unsigned char)0;
            *(unsigned long long*)(sp + ((size_t)t * NN + r) * 16 + 2 * w) = sb;
        }
        __syncthreads();   // B1

        if (lflag[p] != 0ull) {
            // build compact list: wave w handles word w
            const unsigned long long nw = lmask[p][w];
            const unsigned long long ow = omask[w];
            const unsigned long long xw = nw ^ ow;
            const int mybit = (int)((xw >> lane) & 1ull);
            const int pos = (int)__popcll(xw & ((1ull << lane) - 1ull));
            if (mybit) {
                const unsigned row = (unsigned)((w << 6) + lane);
                const unsigned sgn = (unsigned)((nw >> lane) & 1ull) << 15;
                list[(w << 6) + pos] = (unsigned short)(row | sgn);
            }
            if (lane == 0) {
                wcnt[w] = (int)__popcll(xw);
                omask[w] = nw;
            }
            __syncthreads();   // B2: list/wcnt ready

            // apply: counted loops (compiler-unrolled, pipelined loads);
            // ascending rows, sign = new bit -> same order as round 8.
#pragma unroll 1
            for (int w2 = 0; w2 < 8; ++w2) {
                const int n2 = wcnt[w2];
                const unsigned short* lp = list + (w2 << 6);
                for (int j = 0; j < n2; ++j) {
                    const unsigned ent = lp[j];
                    const float gv = Gc[((size_t)(ent & 511u)) << 9];
                    acc += (ent & 0x8000u) ? gv : -gv;
                }
            }
        }

        v = fmaf(dd, v, fmaf(e, acc, cg));
        em *= dd;
    }
}

// ---- Expand: out[t][b][o] = bit b of sp[t][o]. Coalesced float4 stores.
__global__ __launch_bounds__(256) void expand_kernel(
    const unsigned* __restrict__ sp, float* __restrict__ out)
{
    const int tid = threadIdx.x;
    const int t = blockIdx.x >> 3;
    const int bt8 = blockIdx.x & 7;

    __shared__ uint2 sh[NN];
    const uint2* spw = (const uint2*)sp;
    sh[tid]       = spw[((size_t)t * NN + tid) * 8 + bt8];
    sh[tid + 256] = spw[((size_t)t * NN + tid + 256) * 8 + bt8];
    __syncthreads();

    const int b = bt8 * 64 + (tid >> 2);
    const int sub = tid & 3;
    const int rw = (tid >> 2) >> 5;
    const int bit = b & 31;
    float* op = out + (size_t)t * (NN * NN) + (size_t)b * NN;

#pragma unroll 4
    for (int i = 0; i < 32; ++i) {
        const int o = sub * 4 + i * 16;
        const uint2 w0 = sh[o];
        const uint2 w1 = sh[o + 1];
        const uint2 w2 = sh[o + 2];
        const uint2 w3 = sh[o + 3];
        float4 f;
        f.x = (float)(((rw ? w0.y : w0.x) >> bit) & 1u);
        f.y = (float)(((rw ? w1.y : w1.x) >> bit) & 1u);
        f.z = (float)(((rw ? w2.y : w2.x) >> bit) & 1u);
        f.w = (float)(((rw ? w3.y : w3.x) >> bit) & 1u);
        *(float4*)(op + o) = f;
    }
}

// ---- Fallback (tiny ws): round-1 step kernel with direct strided writes.
__global__ __launch_bounds__(256) void snn_step_kernel(
    const float* __restrict__ M, const float* __restrict__ G,
    const float* __restrict__ V0, const float* __restrict__ gs,
    const float* __restrict__ alpha, const float* __restrict__ eta,
    const float* __restrict__ beta, float* __restrict__ out, int T)
{
    const int j = threadIdx.x;
    const int r0 = blockIdx.x * 2;
    const int c0 = 2 * j;
    const float a = alpha[0], e = eta[0], bt = beta[0];
    const float kk = 0.2f, dd = 0.36787944117144233f, Vth = 0.2f;

    float v00 = V0[r0 * NN + c0];
    float v01 = V0[r0 * NN + c0 + 1];
    float v10 = V0[(r0 + 1) * NN + c0];
    float v11 = V0[(r0 + 1) * NN + c0 + 1];
    const float m00 = M[r0 * NN + c0];
    const float m01 = M[r0 * NN + c0 + 1];
    const float m10 = M[(r0 + 1) * NN + c0];
    const float m11 = M[(r0 + 1) * NN + c0 + 1];
    const float gs0 = gs[c0];
    const float gs1 = gs[c0 + 1];

    __shared__ float2 hp[NN];
    float em = 1.0f;
    const float2* Gcol = (const float2*)G + j;

    for (int t = 0; t < T; ++t) {
        const float u00 = kk * (m00 * em + a * v00);
        const float u01 = kk * (m01 * em + a * v01);
        const float u10 = kk * (m10 * em + a * v10);
        const float u11 = kk * (m11 * em + a * v11);

        float* outp = out + (size_t)t * (NN * NN);
        float2 sA = make_float2(u00 > Vth ? 1.f : 0.f, u10 > Vth ? 1.f : 0.f);
        float2 sB = make_float2(u01 > Vth ? 1.f : 0.f, u11 > Vth ? 1.f : 0.f);
        *(float2*)(outp + (size_t)c0 * NN + r0) = sA;
        *(float2*)(outp + (size_t)(c0 + 1) * NN + r0) = sB;

        hp[c0]     = make_float2(u00 > 0.f ? 1.f : 0.f, u10 > 0.f ? 1.f : 0.f);
        hp[c0 + 1] = make_float2(u01 > 0.f ? 1.f : 0.f, u11 > 0.f ? 1.f : 0.f);
        __syncthreads();

        float acc00 = 0.f, acc01 = 0.f, acc10 = 0.f, acc11 = 0.f;
#pragma unroll 8
        for (int bp = 0; bp < NN; ++bp) {
            float2 h = hp[bp];
            float2 g = Gcol[(size_t)bp * 256];
            acc00 = fmaf(h.x, g.x, acc00);
            acc01 = fmaf(h.x, g.y, acc01);
            acc10 = fmaf(h.y, g.x, acc10);
            acc11 = fmaf(h.y, g.y, acc11);
        }

        v00 = dd * v00 + e * (acc00 + bt * gs0);
        v01 = dd * v01 + e * (acc01 + bt * gs1);
        v10 = dd * v10 + e * (acc10 + bt * gs0);
        v11 = dd * v11 + e * (acc11 + bt * gs1);
        em *= dd;
        __syncthreads();
    }
}

extern "C" void kernel_launch(void* const* d_in, const int* in_sizes, int n_in,
                              void* d_out, int out_size, void* d_ws, size_t ws_size,
                              hipStream_t stream)
{
    const float* x     = (const float*)d_in[0];
    const float* W     = (const float*)d_in[1];
    const float* bias  = (const float*)d_in[2];
    const float* alpha = (const float*)d_in[3];
    const float* eta   = (const float*)d_in[4];
    const float* beta  = (const float*)d_in[5];
    const float* P0    = (const float*)d_in[6];
    (void)in_sizes; (void)n_in;

    const int T = out_size / (NN * NN);

    float* ws  = (float*)d_ws;
    float* M   = ws;                           // [512,512] final (relu+bias)
    float* V0  = ws + NN * NN;                 // [512,512]
    float* G   = ws + 2 * NN * NN;             // [512,512] = 1 MB
    float* gsv = ws + 3 * NN * NN;             // [512]
    unsigned* sp = (unsigned*)(gsv + NN);      // [T][512][16] words

    const size_t need_main = ((size_t)3 * NN * NN + NN) * 4 + (size_t)T * NN * 16 * 4;

    hipLaunchKernelGGL(gemm_stack2_kernel, dim3(384), dim3(256), 0, stream,
                       x, W, P0, bias, M, V0, G);
    hipLaunchKernelGGL(colsum_kernel, dim3(8), dim3(256), 0, stream, G, gsv);

    if (ws_size >= need_main) {
        hipLaunchKernelGGL(snn_bits3_kernel, dim3(NN), dim3(512), 0, stream,
                           M, G, V0, gsv, alpha, eta, beta, sp, T);
        hipLaunchKernelGGL(expand_kernel, dim3(T * 8), dim3(256), 0, stream,
                           sp, (float*)d_out);
    } else {
        hipLaunchKernelGGL(snn_step_kernel, dim3(256), dim3(256), 0, stream,
                           M, G, V0, gsv, alpha, eta, beta, (float*)d_out, T);
    }
}

// Round 10
// 140.388 us; speedup vs baseline: 1.2715x; 1.2715x over previous
//
#include <hip/hip_runtime.h>

// B = IN = OUT = 512; T from out_size.
// v_t = P_t @ x^T [OUT,B]; G = x@x^T [B,B]
//   u = k*(M*e^{-t} + a*v);  h = (u>0);  s = (u>0.2)
//   v' = d*v + e*(h@G + bt*colsum(G))
// Round-10: snn delta-apply rebuilt around INDEPENDENT batched loads. One
// global compact list of flipped rows (cross-wave prefix, ascending (word,lane)
// order -> summation order identical to rounds 8/9). Apply loop is hand-
// unrolled 8-wide: one uint4 LDS read -> 8 independent coalesced G loads ->
// 8 clamp-selected adds (acc += valid ? +-g : 0.0f; exact). This removes the
// serialized per-entry L2 chain that made rounds 8/9 regress. GEMM unchanged
// (will surface in top-5 counters next round once snn drops below it).

#define NN 512

// ---- Stacked NT GEMM: grid 384 = 3 outputs x (16 row-tiles x 8 col-tiles).
// out 0: M = relu(W·x^T + b); out 1: V0 = P0·x^T; out 2: G = x·x^T.
// 32x64 tile, 256 thr, 2x4 micro, KC=32, reg double-buffer.
__global__ __launch_bounds__(256) void gemm_stack2_kernel(
    const float* __restrict__ x, const float* __restrict__ W,
    const float* __restrict__ P0, const float* __restrict__ bias,
    float* __restrict__ M, float* __restrict__ V0, float* __restrict__ G)
{
    const int tid = threadIdx.x;
    const int bid = blockIdx.x;          // 0..383
    const int out = bid >> 7;            // 0..2
    const int tl = bid & 127;            // 0..127
    const int rb = (tl >> 3) << 5;       // 16 row-tiles of 32
    const int cb = (tl & 7) << 6;        // 8 col-tiles of 64

    const float* A = ((out == 0) ? W : (out == 1) ? P0 : x) + (size_t)rb * NN;
    float* D = (out == 0) ? M : (out == 1) ? V0 : G;

    const int tx = tid & 15;             // cols 4tx..4tx+3
    const int ty = tid >> 4;             // rows 2ty, 2ty+1

    __shared__ float At[32][36];
    __shared__ float Bt[32][68];

    const int ar = tid >> 3;             // 0..31
    const int ak = (tid & 7) << 2;       // 0,4,...,28
    const int br = tid >> 2;             // 0..63
    const int bk = (tid & 3) << 3;       // 0,8,16,24

    float acc[2][4] = {{0.f, 0.f, 0.f, 0.f}, {0.f, 0.f, 0.f, 0.f}};

    float4 av4 = *(const float4*)(A + (size_t)ar * NN + ak);
    float4 bv4a = *(const float4*)(x + (size_t)(cb + br) * NN + bk);
    float4 bv4b = *(const float4*)(x + (size_t)(cb + br) * NN + bk + 4);

    for (int c = 0; c < 16; ++c) {
        __syncthreads();
        At[ak + 0][ar] = av4.x; At[ak + 1][ar] = av4.y;
        At[ak + 2][ar] = av4.z; At[ak + 3][ar] = av4.w;
        Bt[bk + 0][br] = bv4a.x; Bt[bk + 1][br] = bv4a.y;
        Bt[bk + 2][br] = bv4a.z; Bt[bk + 3][br] = bv4a.w;
        Bt[bk + 4][br] = bv4b.x; Bt[bk + 5][br] = bv4b.y;
        Bt[bk + 6][br] = bv4b.z; Bt[bk + 7][br] = bv4b.w;
        __syncthreads();

        if (c < 15) {
            const int k0 = (c + 1) << 5;
            av4 = *(const float4*)(A + (size_t)ar * NN + k0 + ak);
            bv4a = *(const float4*)(x + (size_t)(cb + br) * NN + k0 + bk);
            bv4b = *(const float4*)(x + (size_t)(cb + br) * NN + k0 + bk + 4);
        }

#pragma unroll
        for (int k = 0; k < 32; ++k) {
            const float2 av = *(const float2*)&At[k][2 * ty];
            const float4 bv = *(const float4*)&Bt[k][4 * tx];
            acc[0][0] = fmaf(av.x, bv.x, acc[0][0]);
            acc[0][1] = fmaf(av.x, bv.y, acc[0][1]);
            acc[0][2] = fmaf(av.x, bv.z, acc[0][2]);
            acc[0][3] = fmaf(av.x, bv.w, acc[0][3]);
            acc[1][0] = fmaf(av.y, bv.x, acc[1][0]);
            acc[1][1] = fmaf(av.y, bv.y, acc[1][1]);
            acc[1][2] = fmaf(av.y, bv.z, acc[1][2]);
            acc[1][3] = fmaf(av.y, bv.w, acc[1][3]);
        }
    }

#pragma unroll
    for (int i = 0; i < 2; ++i) {
        const int r = rb + 2 * ty + i;
        float4 o = make_float4(acc[i][0], acc[i][1], acc[i][2], acc[i][3]);
        if (out == 0) {
            const float bb = bias[r];
            o.x = fmaxf(o.x + bb, 0.f); o.y = fmaxf(o.y + bb, 0.f);
            o.z = fmaxf(o.z + bb, 0.f); o.w = fmaxf(o.w + bb, 0.f);
        }
        *(float4*)(D + (size_t)r * NN + cb + 4 * tx) = o;
    }
}

// ---- colsum: 8 blocks x 256 thr
__global__ __launch_bounds__(256) void colsum_kernel(
    const float* __restrict__ G, float* __restrict__ gs)
{
    __shared__ float red[4][64];
    const int tid = threadIdx.x;
    const int c = (blockIdx.x << 6) + (tid & 63);
    const int g = tid >> 6;
    float s = 0.f;
    for (int bp = 128 * g; bp < 128 * g + 128; ++bp) s += G[(size_t)bp * NN + c];
    if (g > 0) red[g][tid & 63] = s;
    __syncthreads();
    if (g == 0) gs[c] = ((s + red[1][tid & 63]) + red[2][tid & 63]) + red[3][tid & 63];
}

// ---- Main recurrence: 512 blocks x 512 threads. Thread owns col c = tid.
// Frozen steps: 1 barrier + 8B flag check. Transient steps: build one global
// compact list of flipped rows (cross-wave prefix), then apply 8-wide with
// independent batched G loads and exact zero-select for the tail.
__global__ __launch_bounds__(512) void snn_bits4_kernel(
    const float* __restrict__ M, const float* __restrict__ G,
    const float* __restrict__ V0, const float* __restrict__ gs,
    const float* __restrict__ alpha, const float* __restrict__ eta,
    const float* __restrict__ beta, unsigned* __restrict__ sp, int T)
{
    const int tid = threadIdx.x;
    const int w = tid >> 6;
    const int lane = tid & 63;
    const int r = blockIdx.x;

    __shared__ unsigned long long lmask[2][8];
    __shared__ unsigned long long lflag[2];
    __shared__ unsigned long long omask[8];                     // last-applied h words
    __shared__ unsigned short list[512] __attribute__((aligned(16)));  // row(9b)|sign(bit15)
    __shared__ int wcnt[8];

    const float a = alpha[0], e = eta[0], bt = beta[0];
    const float kk = 0.2f;
    const float dd = 0.36787944117144233f;   // exp(-1)
    const float Vth = 0.2f;

    const size_t rc = (size_t)r * NN + tid;
    const float m = M[rc];
    float v = V0[rc];
    const float cg = e * bt * gs[tid];
    const float* Gc = G + tid;

    if (tid < 8) omask[tid] = 0ull;          // acc==0 <-> h==0 baseline: exact
    __syncthreads();

    float acc = 0.f;
    float em = 1.0f;

    for (int t = 0; t < T; ++t) {
        const float u = kk * fmaf(a, v, m * em);
        const unsigned long long hb = __ballot(u > 0.f);
        const unsigned long long sb = __ballot(u > Vth);
        const int p = t & 1;
        if (lane == 0) {
            lmask[p][w] = hb;
            ((unsigned char*)&lflag[p])[w] = (hb != omask[w]) ? (unsigned char)1 : (unsigned char)0;
            *(unsigned long long*)(sp + ((size_t)t * NN + r) * 16 + 2 * w) = sb;
        }
        __syncthreads();   // B1: masks/flags visible

        if (lflag[p] != 0ull) {
            const unsigned long long nw = lmask[p][w];
            const unsigned long long ow = omask[w];
            const unsigned long long xw = nw ^ ow;
            if (lane == 0) {
                wcnt[w] = (int)__popcll(xw);
                omask[w] = nw;
            }
            __syncthreads();   // B2: wcnt ready

            int base = 0;
            for (int i = 0; i < w; ++i) base += wcnt[i];
            int ntot = base;
            for (int i = w; i < 8; ++i) ntot += wcnt[i];

            if ((xw >> lane) & 1ull) {
                const int pos = (int)__popcll(xw & ((1ull << lane) - 1ull));
                const unsigned row = (unsigned)((w << 6) + lane);
                const unsigned sgn = (unsigned)((nw >> lane) & 1ull) << 15;
                list[base + pos] = (unsigned short)(row | sgn);
            }
            __syncthreads();   // B3: list ready

            // 8-wide apply: 1 uint4 LDS read -> 8 independent G loads ->
            // 8 clamp-selected adds. Tail entries read stale LDS (address is
            // always in-bounds: row&511) but contribute exactly 0.0f.
            for (int j = 0; j < ntot; j += 8) {
                const uint4 le = *(const uint4*)(list + j);
                unsigned ent[8];
                ent[0] = le.x & 0xFFFFu; ent[1] = le.x >> 16;
                ent[2] = le.y & 0xFFFFu; ent[3] = le.y >> 16;
                ent[4] = le.z & 0xFFFFu; ent[5] = le.z >> 16;
                ent[6] = le.w & 0xFFFFu; ent[7] = le.w >> 16;
                float g[8];
#pragma unroll
                for (int i = 0; i < 8; ++i)
                    g[i] = Gc[((size_t)(ent[i] & 511u)) << 9];
#pragma unroll
                for (int i = 0; i < 8; ++i) {
                    const float sgv = (ent[i] & 0x8000u) ? g[i] : -g[i];
                    acc += (j + i < ntot) ? sgv : 0.0f;
                }
            }
        }

        v = fmaf(dd, v, fmaf(e, acc, cg));
        em *= dd;
    }
}

// ---- Expand: out[t][b][o] = bit b of sp[t][o]. Coalesced float4 stores.
__global__ __launch_bounds__(256) void expand_kernel(
    const unsigned* __restrict__ sp, float* __restrict__ out)
{
    const int tid = threadIdx.x;
    const int t = blockIdx.x >> 3;
    const int bt8 = blockIdx.x & 7;

    __shared__ uint2 sh[NN];
    const uint2* spw = (const uint2*)sp;
    sh[tid]       = spw[((size_t)t * NN + tid) * 8 + bt8];
    sh[tid + 256] = spw[((size_t)t * NN + tid + 256) * 8 + bt8];
    __syncthreads();

    const int b = bt8 * 64 + (tid >> 2);
    const int sub = tid & 3;
    const int rw = (tid >> 2) >> 5;
    const int bit = b & 31;
    float* op = out + (size_t)t * (NN * NN) + (size_t)b * NN;

#pragma unroll 4
    for (int i = 0; i < 32; ++i) {
        const int o = sub * 4 + i * 16;
        const uint2 w0 = sh[o];
        const uint2 w1 = sh[o + 1];
        const uint2 w2 = sh[o + 2];
        const uint2 w3 = sh[o + 3];
        float4 f;
        f.x = (float)(((rw ? w0.y : w0.x) >> bit) & 1u);
        f.y = (float)(((rw ? w1.y : w1.x) >> bit) & 1u);
        f.z = (float)(((rw ? w2.y : w2.x) >> bit) & 1u);
        f.w = (float)(((rw ? w3.y : w3.x) >> bit) & 1u);
        *(float4*)(op + o) = f;
    }
}

// ---- Fallback (tiny ws): round-1 step kernel with direct strided writes.
__global__ __launch_bounds__(256) void snn_step_kernel(
    const float* __restrict__ M, const float* __restrict__ G,
    const float* __restrict__ V0, const float* __restrict__ gs,
    const float* __restrict__ alpha, const float* __restrict__ eta,
    const float* __restrict__ beta, float* __restrict__ out, int T)
{
    const int j = threadIdx.x;
    const int r0 = blockIdx.x * 2;
    const int c0 = 2 * j;
    const float a = alpha[0], e = eta[0], bt = beta[0];
    const float kk = 0.2f, dd = 0.36787944117144233f, Vth = 0.2f;

    float v00 = V0[r0 * NN + c0];
    float v01 = V0[r0 * NN + c0 + 1];
    float v10 = V0[(r0 + 1) * NN + c0];
    float v11 = V0[(r0 + 1) * NN + c0 + 1];
    const float m00 = M[r0 * NN + c0];
    const float m01 = M[r0 * NN + c0 + 1];
    const float m10 = M[(r0 + 1) * NN + c0];
    const float m11 = M[(r0 + 1) * NN + c0 + 1];
    const float gs0 = gs[c0];
    const float gs1 = gs[c0 + 1];

    __shared__ float2 hp[NN];
    float em = 1.0f;
    const float2* Gcol = (const float2*)G + j;

    for (int t = 0; t < T; ++t) {
        const float u00 = kk * (m00 * em + a * v00);
        const float u01 = kk * (m01 * em + a * v01);
        const float u10 = kk * (m10 * em + a * v10);
        const float u11 = kk * (m11 * em + a * v11);

        float* outp = out + (size_t)t * (NN * NN);
        float2 sA = make_float2(u00 > Vth ? 1.f : 0.f, u10 > Vth ? 1.f : 0.f);
        float2 sB = make_float2(u01 > Vth ? 1.f : 0.f, u11 > Vth ? 1.f : 0.f);
        *(float2*)(outp + (size_t)c0 * NN + r0) = sA;
        *(float2*)(outp + (size_t)(c0 + 1) * NN + r0) = sB;

        hp[c0]     = make_float2(u00 > 0.f ? 1.f : 0.f, u10 > 0.f ? 1.f : 0.f);
        hp[c0 + 1] = make_float2(u01 > 0.f ? 1.f : 0.f, u11 > 0.f ? 1.f : 0.f);
        __syncthreads();

        float acc00 = 0.f, acc01 = 0.f, acc10 = 0.f, acc11 = 0.f;
#pragma unroll 8
        for (int bp = 0; bp < NN; ++bp) {
            float2 h = hp[bp];
            float2 g = Gcol[(size_t)bp * 256];
            acc00 = fmaf(h.x, g.x, acc00);
            acc01 = fmaf(h.x, g.y, acc01);
            acc10 = fmaf(h.y, g.x, acc10);
            acc11 = fmaf(h.y, g.y, acc11);
        }

        v00 = dd * v00 + e * (acc00 + bt * gs0);
        v01 = dd * v01 + e * (acc01 + bt * gs1);
        v10 = dd * v10 + e * (acc10 + bt * gs0);
        v11 = dd * v11 + e * (acc11 + bt * gs1);
        em *= dd;
        __syncthreads();
    }
}

extern "C" void kernel_launch(void* const* d_in, const int* in_sizes, int n_in,
                              void* d_out, int out_size, void* d_ws, size_t ws_size,
                              hipStream_t stream)
{
    const float* x     = (const float*)d_in[0];
    const float* W     = (const float*)d_in[1];
    const float* bias  = (const float*)d_in[2];
    const float* alpha = (const float*)d_in[3];
    const float* eta   = (const float*)d_in[4];
    const float* beta  = (const float*)d_in[5];
    const float* P0    = (const float*)d_in[6];
    (void)in_sizes; (void)n_in;

    const int T = out_size / (NN * NN);

    float* ws  = (float*)d_ws;
    float* M   = ws;                           // [512,512] final (relu+bias)
    float* V0  = ws + NN * NN;                 // [512,512]
    float* G   = ws + 2 * NN * NN;             // [512,512] = 1 MB
    float* gsv = ws + 3 * NN * NN;             // [512]
    unsigned* sp = (unsigned*)(gsv + NN);      // [T][512][16] words

    const size_t need_main = ((size_t)3 * NN * NN + NN) * 4 + (size_t)T * NN * 16 * 4;

    hipLaunchKernelGGL(gemm_stack2_kernel, dim3(384), dim3(256), 0, stream,
                       x, W, P0, bias, M, V0, G);
    hipLaunchKernelGGL(colsum_kernel, dim3(8), dim3(256), 0, stream, G, gsv);

    if (ws_size >= need_main) {
        hipLaunchKernelGGL(snn_bits4_kernel, dim3(NN), dim3(512), 0, stream,
                           M, G, V0, gsv, alpha, eta, beta, sp, T);
        hipLaunchKernelGGL(expand_kernel, dim3(T * 8), dim3(256), 0, stream,
                           sp, (float*)d_out);
    } else {
        hipLaunchKernelGGL(snn_step_kernel, dim3(256), dim3(256), 0, stream,
                           M, G, V0, gsv, alpha, eta, beta, (float*)d_out, T);
    }
}